// Round 3
// baseline (156.381 us; speedup 1.0000x reference)
//
#include <hip/hip_runtime.h>
#include <math.h>

// B=16384, S=64, V=25, E=64, H=64, 4H=256, C=3
// gates[B,256] = x[B,89] @ W^T via mfma_f32_16x16x32_bf16, K padded to 3 chunks of 32.
// chunk0 = msg (k=0..24, pad 0), chunk1 = h k=0..31, chunk2 = h k=32..63.

using bf16x8 = __attribute__((ext_vector_type(8))) short;
using f32x4  = __attribute__((ext_vector_type(4))) float;

__device__ __forceinline__ unsigned short f2bf(float x) {
    unsigned int u = __float_as_uint(x);
    u += 0x7FFFu + ((u >> 16) & 1u);           // RNE
    return (unsigned short)(u >> 16);
}
__device__ __forceinline__ float bf2f(unsigned short h) {
    return __uint_as_float(((unsigned int)h) << 16);
}
__device__ __forceinline__ float fsig(float x) {
    float t = __builtin_amdgcn_exp2f(-1.4426950408889634f * x);
    return __builtin_amdgcn_rcpf(1.0f + t);
}
__device__ __forceinline__ float ftanh(float x) {
    float t = __builtin_amdgcn_exp2f(-2.8853900817779268f * fabsf(x));
    float r = (1.0f - t) * __builtin_amdgcn_rcpf(1.0f + t);
    return copysignf(r, x);
}

// B-fragment layout for 16x16x32: lane holds B[k=(lane>>4)*8+j][col=(lane&15)+16*tile], j=0..7.
// wfrag[((ch*16+t)*64+lane)*8+j], bf16. ch0: comb[k][g] (k<25 else 0); ch1/2: Whh[g][k].
__global__ void prep_kernel(const float* __restrict__ emb,
                            const float* __restrict__ Wih,
                            const float* __restrict__ Whh,
                            const float* __restrict__ bih,
                            const float* __restrict__ bhh,
                            unsigned short* __restrict__ wfrag,
                            float* __restrict__ biasc) {
    const int b = blockIdx.x, tid = threadIdx.x;
    if (b < 48) {
        const int ch = b >> 4, t = b & 15;
        const int lane = tid >> 3, j = tid & 7;
        const int kloc = (lane >> 4) * 8 + j;       // 0..31
        const int g = (lane & 15) + 16 * t;         // 0..255
        float v = 0.f;
        if (ch == 0) {
            if (kloc < 25) {
                const float* ep = emb + kloc * 64;
                const float* wp = Wih + g * 64;
                float s = 0.f;
                #pragma unroll
                for (int e = 0; e < 64; ++e) s = fmaf(ep[e], wp[e], s);
                v = s;
            }
        } else {
            v = Whh[g * 64 + (ch - 1) * 32 + kloc];
        }
        wfrag[((ch * 16 + t) * 64 + lane) * 8 + j] = f2bf(v);
    } else if (tid < 256) {
        biasc[tid] = bih[tid] + bhh[tid];
    }
}

#define LOADMSG(DST, SS)                                                     \
    {                                                                        \
        const float* p_ = mrow + (SS) * 25 + kq;                             \
        if (kq < 24) {                                                       \
            _Pragma("unroll") for (int j = 0; j < 8; ++j) DST[j] = p_[j];    \
        } else {                                                             \
            DST[0] = p_[0];                                                  \
            _Pragma("unroll") for (int j = 1; j < 8; ++j) DST[j] = 0.f;      \
        }                                                                    \
    }

#define STEP(S, CURB, NXTB, MC, MN)                                          \
    {                                                                        \
        if ((S) < 63) LOADMSG(MN, (S) + 1)                                   \
        bf16x8 amsg;                                                         \
        _Pragma("unroll") for (int j = 0; j < 8; ++j)                        \
            amsg[j] = (short)f2bf(MC[j]);                                    \
        bf16x8 ahi[2], alo[2];                                               \
        _Pragma("unroll") for (int ch = 0; ch < 2; ++ch) {                   \
            int off_ = (hrow_rd * 128 + ch * 64 + kq * 2) ^ swz_rd;          \
            ahi[ch] = *(const bf16x8*)((CURB) + off_);                       \
            alo[ch] = *(const bf16x8*)((CURB) + 4096 + off_);                \
        }                                                                    \
        f32x4 acc[4];                                                        \
        _Pragma("unroll") for (int i = 0; i < 4; ++i)                        \
            acc[i] = (f32x4){bias[i], bias[i], bias[i], bias[i]};            \
        _Pragma("unroll") for (int i = 0; i < 4; ++i)                        \
            acc[i] = __builtin_amdgcn_mfma_f32_16x16x32_bf16(                \
                amsg, w[0][i], acc[i], 0, 0, 0);                             \
        _Pragma("unroll") for (int ch = 0; ch < 2; ++ch) {                   \
            _Pragma("unroll") for (int i = 0; i < 4; ++i)                    \
                acc[i] = __builtin_amdgcn_mfma_f32_16x16x32_bf16(            \
                    ahi[ch], w[1 + ch][i], acc[i], 0, 0, 0);                 \
            _Pragma("unroll") for (int i = 0; i < 4; ++i)                    \
                acc[i] = __builtin_amdgcn_mfma_f32_16x16x32_bf16(            \
                    alo[ch], w[1 + ch][i], acc[i], 0, 0, 0);                 \
        }                                                                    \
        _Pragma("unroll") for (int q = 0; q < 4; ++q) {                      \
            float ig = fsig(acc[0][q]);                                      \
            float fg = fsig(acc[1][q]);                                      \
            float gg = ftanh(acc[2][q]);                                     \
            float og = fsig(acc[3][q]);                                      \
            float cn = fmaf(fg, c[q], ig * gg);                              \
            c[q] = cn;                                                       \
            float hn = og * ftanh(cn);                                       \
            unsigned short hh_ = f2bf(hn);                                   \
            unsigned short hl_ = f2bf(hn - bf2f(hh_));                       \
            int rw_ = 16 * rg + lq * 4 + q;                                  \
            int offw_ = ((rw_ * 128) + uidx * 2) ^ ((rw_ & 7) << 4);         \
            *(unsigned short*)((NXTB) + offw_) = hh_;                        \
            *(unsigned short*)((NXTB) + 4096 + offw_) = hl_;                 \
        }                                                                    \
        __syncthreads();                                                     \
    }

__global__ __launch_bounds__(512, 4) void lstm_mfma(
    const float* __restrict__ msgs,
    const unsigned short* __restrict__ wfrag,
    const float* __restrict__ biasc,
    const float* __restrict__ fcw,
    const float* __restrict__ fcb,
    float* __restrict__ out)
{
    // double-buffered h: buf = {hhi[32][64]bf16 | hlo[32][64]bf16} = 8KB, x2
    __shared__ __align__(16) char lds[16384];

    const int tid  = threadIdx.x;
    const int lane = tid & 63;
    const int wid  = __builtin_amdgcn_readfirstlane(tid >> 6); // 0..7
    const int rg   = wid >> 2;                 // row group: rows 16*rg..+15
    const int cg   = wid & 3;                  // unit group: units 16*cg..+15
    const int l16  = lane & 15;
    const int lq   = lane >> 4;
    const int row0 = blockIdx.x * 32;
    const int uidx = l16 + 16 * cg;            // this lane's unit column
    const int kq   = lq * 8;                   // k base within chunk

    // weight fragments in VGPRs for the whole kernel: tiles cg+4i (i = gate class)
    bf16x8 w[3][4];
    #pragma unroll
    for (int ch = 0; ch < 3; ++ch)
        #pragma unroll
        for (int i = 0; i < 4; ++i)
            w[ch][i] = *(const bf16x8*)(wfrag + ((ch * 16 + cg + 4 * i) * 64 + lane) * 8);

    float bias[4];
    #pragma unroll
    for (int i = 0; i < 4; ++i) bias[i] = biasc[uidx + 64 * i];

    // zero h buffer 0 (hi+lo = 8KB)
    for (int idx = tid; idx < 2048; idx += 512) ((unsigned int*)lds)[idx] = 0u;

    float c[4] = {0.f, 0.f, 0.f, 0.f};

    const float* mrow = msgs + (long)(row0 + 16 * rg + l16) * 1600;
    const int hrow_rd = 16 * rg + l16;         // A-frag row this lane reads
    const int swz_rd  = (hrow_rd & 7) << 4;

    float m0[8], m1[8];
    LOADMSG(m0, 0)
    __syncthreads();

    char* b0 = (char*)lds;
    char* b1 = b0 + 8192;
    for (int s2 = 0; s2 < 64; s2 += 2) {
        STEP(s2,     b0, b1, m0, m1)
        STEP(s2 + 1, b1, b0, m1, m0)
    }

    // final h is in buf0 (hi+lo). FC epilogue: thread -> (row, class)
    if (tid < 128) {
        const int r = tid >> 2, cls = tid & 3;
        if (cls < 3) {
            float a = fcb[cls];
            const int swz = (r & 7) << 4;
            #pragma unroll
            for (int u = 0; u < 64; ++u) {
                int off = (r * 128 + u * 2) ^ swz;
                float hv = bf2f(*(const unsigned short*)(b0 + off))
                         + bf2f(*(const unsigned short*)(b0 + 4096 + off));
                a = fmaf(hv, fcw[cls * 64 + u], a);
            }
            out[(row0 + r) * 3 + cls] = a;
        }
    }
}

extern "C" void kernel_launch(void* const* d_in, const int* in_sizes, int n_in,
                              void* d_out, int out_size, void* d_ws, size_t ws_size,
                              hipStream_t stream) {
    const float* msgs = (const float*)d_in[0];
    const float* emb  = (const float*)d_in[1];
    const float* Wih  = (const float*)d_in[2];
    const float* Whh  = (const float*)d_in[3];
    const float* bih  = (const float*)d_in[4];
    const float* bhh  = (const float*)d_in[5];
    const float* fcw  = (const float*)d_in[6];
    const float* fcb  = (const float*)d_in[7];
    float* out = (float*)d_out;

    // ws: wfrag bf16[3*16*64*8] = 49152 B | biasc f32[256] = 1024 B
    unsigned short* wfrag = (unsigned short*)d_ws;
    float* biasc = (float*)((char*)d_ws + 49152);

    prep_kernel<<<49, 512, 0, stream>>>(emb, Wih, Whh, bih, bhh, wfrag, biasc);
    lstm_mfma<<<16384 / 32, 512, 0, stream>>>(msgs, wfrag, biasc, fcw, fcb, out);
}

// Round 4
// 133.155 us; speedup vs baseline: 1.1744x; 1.1744x over previous
//
#include <hip/hip_runtime.h>
#include <math.h>

// B=16384, S=64, V=25, E=64, H=64, 4H=256, C=3
// gates[B,256] = x[B,89] @ W^T via mfma_f32_16x16x32_bf16, K = 3 chunks of 32:
// chunk0 = msg k=0..24, k=25 carries 1.0 (bias row), k>25 pad 0; chunk1/2 = h (single bf16).
// Block = 4 waves (256 thr) = 16 batch rows; wave cg owns units [16cg,16cg+16) x 4 gate classes.

using bf16x8 = __attribute__((ext_vector_type(8))) short;
using f32x4  = __attribute__((ext_vector_type(4))) float;

__device__ __forceinline__ unsigned short f2bf(float x) {
    unsigned int u = __float_as_uint(x);
    u += 0x7FFFu + ((u >> 16) & 1u);           // RNE
    return (unsigned short)(u >> 16);
}
__device__ __forceinline__ float bf2f(unsigned short h) {
    return __uint_as_float(((unsigned int)h) << 16);
}
__device__ __forceinline__ float fsig(float x) {
    float t = __builtin_amdgcn_exp2f(-1.4426950408889634f * x);
    return __builtin_amdgcn_rcpf(1.0f + t);
}
__device__ __forceinline__ float ftanh(float x) {
    float t = __builtin_amdgcn_exp2f(-2.8853900817779268f * fabsf(x));
    float r = (1.0f - t) * __builtin_amdgcn_rcpf(1.0f + t);
    return copysignf(r, x);
}

// B-fragment layout for 16x16x32: lane holds B[k=(lane>>4)*8+j][col=(lane&15)+16*tile], j=0..7.
// wfrag[((ch*16+t)*64+lane)*8+j], bf16. ch0: comb[k][g] (k<25), k==25 -> bias; ch1/2: Whh[g][k].
__global__ void prep_kernel(const float* __restrict__ emb,
                            const float* __restrict__ Wih,
                            const float* __restrict__ Whh,
                            const float* __restrict__ bih,
                            const float* __restrict__ bhh,
                            unsigned short* __restrict__ wfrag) {
    const int b = blockIdx.x, tid = threadIdx.x;
    const int ch = b >> 4, t = b & 15;
    const int lane = tid >> 3, j = tid & 7;
    const int kloc = (lane >> 4) * 8 + j;       // 0..31
    const int g = (lane & 15) + 16 * t;         // 0..255
    float v = 0.f;
    if (ch == 0) {
        if (kloc < 25) {
            const float* ep = emb + kloc * 64;
            const float* wp = Wih + g * 64;
            float s = 0.f;
            #pragma unroll
            for (int e = 0; e < 64; ++e) s = fmaf(ep[e], wp[e], s);
            v = s;
        } else if (kloc == 25) {
            v = bih[g] + bhh[g];                // bias row (exact: 0.0 / 1.0)
        }
    } else {
        v = Whh[g * 64 + (ch - 1) * 32 + kloc];
    }
    wfrag[((ch * 16 + t) * 64 + lane) * 8 + j] = f2bf(v);
}

#define LOADMSG(DST, SS)                                                     \
    {                                                                        \
        const float* p_ = mrow + (SS) * 25 + kq;                             \
        if (kq < 24) {                                                       \
            _Pragma("unroll") for (int j = 0; j < 8; ++j)                    \
                DST[j] = (short)f2bf(p_[j]);                                 \
        } else {                                                             \
            DST[0] = (short)f2bf(p_[0]);                                     \
            DST[1] = (short)0x3F80;   /* 1.0 -> bias row k=25 */             \
            _Pragma("unroll") for (int j = 2; j < 8; ++j) DST[j] = 0;        \
        }                                                                    \
    }

#define STEP(S, CURB, NXTB, MC, MN)                                          \
    {                                                                        \
        if ((S) < 63) LOADMSG(MN, (S) + 1)                                   \
        bf16x8 ah[2];                                                        \
        _Pragma("unroll") for (int ch = 0; ch < 2; ++ch) {                   \
            int off_ = (l16 * 128 + ch * 64 + kq * 2) ^ swz_rd;              \
            ah[ch] = *(const bf16x8*)((CURB) + off_);                        \
        }                                                                    \
        f32x4 acc[4];                                                        \
        _Pragma("unroll") for (int i = 0; i < 4; ++i)                        \
            acc[i] = (f32x4){0.f, 0.f, 0.f, 0.f};                            \
        _Pragma("unroll") for (int i = 0; i < 4; ++i)                        \
            acc[i] = __builtin_amdgcn_mfma_f32_16x16x32_bf16(                \
                MC, w[0][i], acc[i], 0, 0, 0);                               \
        _Pragma("unroll") for (int ch = 0; ch < 2; ++ch)                     \
            _Pragma("unroll") for (int i = 0; i < 4; ++i)                    \
                acc[i] = __builtin_amdgcn_mfma_f32_16x16x32_bf16(            \
                    ah[ch], w[1 + ch][i], acc[i], 0, 0, 0);                  \
        _Pragma("unroll") for (int q = 0; q < 4; ++q) {                      \
            float ig = fsig(acc[0][q]);                                      \
            float fg = fsig(acc[1][q]);                                      \
            float gg = ftanh(acc[2][q]);                                     \
            float og = fsig(acc[3][q]);                                      \
            float cn = fmaf(fg, c[q], ig * gg);                              \
            c[q] = cn;                                                       \
            float hn = og * ftanh(cn);                                       \
            int rw_ = lq * 4 + q;                                            \
            int offw_ = ((rw_ * 128) + uidx * 2) ^ ((rw_ & 7) << 4);         \
            *(unsigned short*)((NXTB) + offw_) = f2bf(hn);                   \
        }                                                                    \
        __syncthreads();                                                     \
    }

__global__ __launch_bounds__(256, 4) void lstm_mfma(
    const float* __restrict__ msgs,
    const unsigned short* __restrict__ wfrag,
    const float* __restrict__ fcw,
    const float* __restrict__ fcb,
    float* __restrict__ out)
{
    // double-buffered h: buf = h[16 rows][64 units] bf16 = 2KB, x2
    __shared__ __align__(16) char lds[4096];

    const int tid  = threadIdx.x;
    const int lane = tid & 63;
    const int cg   = __builtin_amdgcn_readfirstlane(tid >> 6); // 0..3 (SGPR)
    const int l16  = lane & 15;
    const int lq   = lane >> 4;
    const int row0 = blockIdx.x * 16;
    const int uidx = l16 + 16 * cg;            // this lane's unit column
    const int kq   = lq * 8;                   // k base within chunk

    // weight fragments in VGPRs: tiles cg+4i (i = gate class), 3 chunks
    bf16x8 w[3][4];
    #pragma unroll
    for (int ch = 0; ch < 3; ++ch)
        #pragma unroll
        for (int i = 0; i < 4; ++i)
            w[ch][i] = *(const bf16x8*)(wfrag + ((ch * 16 + cg + 4 * i) * 64 + lane) * 8);

    // zero h buffer 0 (2KB)
    for (int idx = tid; idx < 512; idx += 256) ((unsigned int*)lds)[idx] = 0u;

    float c[4] = {0.f, 0.f, 0.f, 0.f};

    const float* mrow = msgs + (long)(row0 + l16) * 1600;
    const int swz_rd  = (l16 & 7) << 4;

    bf16x8 m0, m1;
    LOADMSG(m0, 0)
    __syncthreads();

    char* b0 = (char*)lds;
    char* b1 = b0 + 2048;
    for (int s2 = 0; s2 < 64; s2 += 2) {
        STEP(s2,     b0, b1, m0, m1)
        STEP(s2 + 1, b1, b0, m1, m0)
    }

    // final h in b0. FC epilogue: thread -> (row, class)
    if (tid < 64) {
        const int r = tid >> 2, cls = tid & 3;
        if (cls < 3) {
            float a = fcb[cls];
            const int swz = (r & 7) << 4;
            #pragma unroll
            for (int u = 0; u < 64; ++u) {
                int off = (r * 128 + u * 2) ^ swz;
                float hv = bf2f(*(const unsigned short*)(b0 + off));
                a = fmaf(hv, fcw[cls * 64 + u], a);
            }
            out[(row0 + r) * 3 + cls] = a;
        }
    }
}

extern "C" void kernel_launch(void* const* d_in, const int* in_sizes, int n_in,
                              void* d_out, int out_size, void* d_ws, size_t ws_size,
                              hipStream_t stream) {
    const float* msgs = (const float*)d_in[0];
    const float* emb  = (const float*)d_in[1];
    const float* Wih  = (const float*)d_in[2];
    const float* Whh  = (const float*)d_in[3];
    const float* bih  = (const float*)d_in[4];
    const float* bhh  = (const float*)d_in[5];
    const float* fcw  = (const float*)d_in[6];
    const float* fcb  = (const float*)d_in[7];
    float* out = (float*)d_out;

    // ws: wfrag bf16[3*16*64*8] = 49152 B
    unsigned short* wfrag = (unsigned short*)d_ws;

    prep_kernel<<<48, 512, 0, stream>>>(emb, Wih, Whh, bih, bhh, wfrag);
    lstm_mfma<<<16384 / 16, 256, 0, stream>>>(msgs, wfrag, fcw, fcb, out);
}